// Round 4
// baseline (1740.277 us; speedup 1.0000x reference)
//
#include <hip/hip_runtime.h>

typedef __bf16 bf16x8 __attribute__((ext_vector_type(8)));
typedef float f32x16 __attribute__((ext_vector_type(16)));

#define LN_EPS 1e-5f
#define AS1 __attribute__((address_space(1)))
#define AS3 __attribute__((address_space(3)))

__device__ __forceinline__ unsigned f2bf_rne(float f) {
    unsigned x = __float_as_uint(f);
    return (x + 0x7fffu + ((x >> 16) & 1u)) >> 16;  // round-to-nearest-even, finite inputs
}

__device__ __forceinline__ float bf2f(unsigned short u) {
    return __uint_as_float((unsigned)u << 16);
}

// ---------------------------------------------------------------------------
// Pack conv_w fp32 (4,27,128,128) -> bf16, K-packed by 8: Wp[oc][k>>3][n][k&7]
// ---------------------------------------------------------------------------
__global__ void pack_w_kernel(const float* __restrict__ cw, unsigned short* __restrict__ Wp, int E) {
    int idx = blockIdx.x * 256 + threadIdx.x;
    if (idx >= E) return;
    float v = cw[idx];
    int n  = idx & 127;
    int c  = (idx >> 7) & 127;
    int oc = idx >> 14;
    Wp[oc * 16384 + (c >> 3) * 1024 + n * 8 + (c & 7)] = (unsigned short)f2bf_rne(v);
}

// Pack w1 fp32 (128,64) -> bf16 K-packed: Wp1[k>>3][n][k&7]
__global__ void pack_w1_kernel(const float* __restrict__ w1, unsigned short* __restrict__ Wp1) {
    int idx = blockIdx.x * 256 + threadIdx.x;
    if (idx >= 8192) return;
    int k = idx >> 6, n = idx & 63;
    Wp1[(k >> 3) * 512 + n * 8 + (k & 7)] = (unsigned short)f2bf_rne(w1[k * 64 + n]);
}

// ---------------------------------------------------------------------------
// Prep: gather table T[o][m] = found ? nbr_idx : M (dummy zero row),
// per-256-tile activity bitmask act[tile].
// ---------------------------------------------------------------------------
__global__ void prep_nbr_kernel(const int* __restrict__ nbr_idx, const float* __restrict__ nbr_mask,
                                int* __restrict__ T, unsigned* __restrict__ act, int M) {
    int m = blockIdx.x * 256 + threadIdx.x;
    if (m >= M) return;
    unsigned bits = 0;
#pragma unroll
    for (int o = 0; o < 27; ++o) {
        bool f = nbr_mask[m * 27 + o] != 0.f;
        int g = f ? nbr_idx[m * 27 + o] : M;
        T[o * M + m] = g;
        bits |= (f ? 1u : 0u) << o;
    }
    atomicOr(&act[m >> 8], bits);
}

// ---------------------------------------------------------------------------
// CSR build: count -> scan (2-level) -> fill
// ---------------------------------------------------------------------------
__global__ void count_kernel(const int* __restrict__ inv, int* __restrict__ cnt, int N) {
    int p = blockIdx.x * 256 + threadIdx.x;
    if (p < N) atomicAdd(&cnt[inv[p]], 1);
}

__global__ void scan1_kernel(const int* __restrict__ cnt, int* __restrict__ starts,
                             int* __restrict__ partials, int M) {
    __shared__ int sdata[256];
    int t = threadIdx.x;
    int base = blockIdx.x * 1024;
    int v[4], tot = 0;
#pragma unroll
    for (int j = 0; j < 4; ++j) {
        int idx = base + t * 4 + j;
        v[j] = idx < M ? cnt[idx] : 0;
        tot += v[j];
    }
    sdata[t] = tot;
    __syncthreads();
    for (int off = 1; off < 256; off <<= 1) {
        int x = (t >= off) ? sdata[t - off] : 0;
        __syncthreads();
        sdata[t] += x;
        __syncthreads();
    }
    int run = sdata[t] - tot;
#pragma unroll
    for (int j = 0; j < 4; ++j) {
        int idx = base + t * 4 + j;
        if (idx < M) starts[idx] = run;
        run += v[j];
    }
    if (t == 255) partials[blockIdx.x] = run;
}

__global__ void scan2_kernel(int* __restrict__ partials, int nb) {
    __shared__ int sdata[256];
    int t = threadIdx.x;
    int v[4], tot = 0;
#pragma unroll
    for (int j = 0; j < 4; ++j) {
        int idx = t * 4 + j;
        v[j] = idx < nb ? partials[idx] : 0;
        tot += v[j];
    }
    sdata[t] = tot;
    __syncthreads();
    for (int off = 1; off < 256; off <<= 1) {
        int x = (t >= off) ? sdata[t - off] : 0;
        __syncthreads();
        sdata[t] += x;
        __syncthreads();
    }
    int run = sdata[t] - tot;
#pragma unroll
    for (int j = 0; j < 4; ++j) {
        int idx = t * 4 + j;
        if (idx < nb) partials[idx] = run;
        run += v[j];
    }
}

__global__ void fill_kernel(const int* __restrict__ inv, const int* __restrict__ starts,
                            const int* __restrict__ partials, int* __restrict__ tmp,
                            int* __restrict__ plist, int N) {
    int p = blockIdx.x * 256 + threadIdx.x;
    if (p >= N) return;
    int v = inv[p];
    int slot = atomicAdd(&tmp[v], 1);
    plist[starts[v] + partials[v >> 10] + slot] = p;
}

// ---------------------------------------------------------------------------
// Voxel encoder: A[v] = mean over points p in voxel of relu(LN(gp[p] @ w_enc + b)).
// One wave per voxel; lane owns channels {2*lane, 2*lane+1}.
// ---------------------------------------------------------------------------
__global__ __launch_bounds__(256) void vox_encode_kernel(
    const float* __restrict__ gp, const float* __restrict__ w_enc,
    const float* __restrict__ b_enc, const float* __restrict__ ln_g,
    const float* __restrict__ ln_b, const int* __restrict__ starts,
    const int* __restrict__ partials, const int* __restrict__ cnt,
    const int* __restrict__ plist, unsigned short* __restrict__ A, int M)
{
    int v = blockIdx.x * 4 + (threadIdx.x >> 6);
    int lane = threadIdx.x & 63;
    if (v >= M) return;
    int st = starts[v] + partials[v >> 10];
    int n = cnt[v];
    const float2* w2p = (const float2*)w_enc;
    float2 be = ((const float2*)b_enc)[lane];
    float2 lg = ((const float2*)ln_g)[lane];
    float2 lb = ((const float2*)ln_b)[lane];
    float a0 = 0.f, a1 = 0.f;
    for (int i = 0; i < n; ++i) {
        int p = plist[st + i];
        float f0 = be.x, f1 = be.y;
#pragma unroll
        for (int k = 0; k < 14; ++k) {
            float gv = gp[p * 14 + k];
            float2 wv = w2p[k * 64 + lane];
            f0 = fmaf(gv, wv.x, f0);
            f1 = fmaf(gv, wv.y, f1);
        }
        float s = f0 + f1;
#pragma unroll
        for (int off = 32; off; off >>= 1) s += __shfl_xor(s, off);
        float mean = s * 0.0078125f;
        float d0 = f0 - mean, d1 = f1 - mean;
        float var = d0 * d0 + d1 * d1;
#pragma unroll
        for (int off = 32; off; off >>= 1) var += __shfl_xor(var, off);
        float rs = rsqrtf(var * 0.0078125f + LN_EPS);
        float h0 = d0 * rs * lg.x + lb.x;
        float h1 = d1 * rs * lg.y + lb.y;
        a0 += h0 > 0.f ? h0 : 0.f;
        a1 += h1 > 0.f ? h1 : 0.f;
    }
    float r = 1.f / (float)n;
    ((unsigned*)A)[v * 64 + lane] = f2bf_rne(a0 * r) | (f2bf_rne(a1 * r) << 16);
}

// ---------------------------------------------------------------------------
// Submanifold conv, pipelined: 256 voxels x 128 ch per block, 8 waves.
// Double-buffered W in LDS (2x32KB); stage(i+1) issued AFTER the barrier so
// its DMA overlaps MFMA(i); gather(i) overlaps MFMA(i-1).
// ---------------------------------------------------------------------------
__global__ __launch_bounds__(512, 4) void subm_conv_kernel(
    const unsigned short* __restrict__ xin,   // (M+1) x 128 bf16, row M zeros
    const unsigned short* __restrict__ Wp,    // 27 x 16 x 128 x 8 bf16 packed
    const int* __restrict__ T, const unsigned* __restrict__ act,
    float* __restrict__ yout, float* __restrict__ stats, int M)
{
    __shared__ uint4 Ws[2][2048];  // 64 KB

    const int tid = threadIdx.x;
    const int lane = tid & 63;
    const int w = tid >> 6;
    const int m0 = blockIdx.x * 256;
    const int rw = w * 32;
    const int q = lane >> 5;
    const int l31 = lane & 31;
    int myrow = m0 + rw + l31;
    if (myrow >= M) myrow = M - 1;  // gather-table guard (stores guarded below)

    f32x16 acc[4];
#pragma unroll
    for (int t = 0; t < 4; ++t)
#pragma unroll
        for (int r = 0; r < 16; ++r) acc[t][r] = 0.f;

    const uint4* xin4 = (const uint4*)xin;
    unsigned amask = act[blockIdx.x];

    int o_cur = __ffs(amask) - 1;  // center offset always active => amask != 0
    amask &= amask - 1;

    {   // stage first W into Ws[0]
        const uint4* WpO4 = (const uint4*)Wp + o_cur * 2048;
#pragma unroll
        for (int rep = 0; rep < 4; ++rep)
            __builtin_amdgcn_global_load_lds(
                (const AS1 unsigned int*)(WpO4 + rep * 512 + tid),
                (AS3 unsigned int*)(&Ws[0][rep * 512 + w * 64]), 16, 0, 0);
    }

    int buf = 0;
    while (o_cur >= 0) {
        int o_next = -1;
        if (amask) { o_next = __ffs(amask) - 1; amask &= amask - 1; }

        // gather this wave's 32 A-rows -> regs (overlaps MFMA of prev offset)
        int g = T[o_cur * M + myrow];
        uint4 af[8];
#pragma unroll
        for (int j = 0; j < 8; ++j) af[j] = xin4[g * 16 + 2 * j + q];

        __syncthreads();  // drains gather(cur)+stage(cur); Ws[buf] valid, Ws[buf^1] free

        if (o_next >= 0) {  // prefetch next W; DMA overlaps MFMA below
            const uint4* WpO4 = (const uint4*)Wp + o_next * 2048;
#pragma unroll
            for (int rep = 0; rep < 4; ++rep)
                __builtin_amdgcn_global_load_lds(
                    (const AS1 unsigned int*)(WpO4 + rep * 512 + tid),
                    (AS3 unsigned int*)(&Ws[buf ^ 1][rep * 512 + w * 64]), 16, 0, 0);
        }

        const bf16x8* wsb = (const bf16x8*)&Ws[buf][0];
#pragma unroll
        for (int ks = 0; ks < 8; ++ks) {
            int kb = (ks << 1) | q;
            bf16x8 a = *(const bf16x8*)&af[ks];
#pragma unroll
            for (int tn = 0; tn < 4; ++tn) {
                bf16x8 b = wsb[kb * 128 + tn * 32 + l31];
                acc[tn] = __builtin_amdgcn_mfma_f32_32x32x16_bf16(a, b, acc[tn], 0, 0, 0);
            }
        }
        buf ^= 1;
        o_cur = o_next;
    }

    // ---- epilogue: store y + BN stats ----
#pragma unroll
    for (int tn = 0; tn < 4; ++tn) {
        int col = tn * 32 + l31;
        float s = 0.f, sq = 0.f;
#pragma unroll
        for (int r = 0; r < 16; ++r) {
            int rloc = (r & 3) + 8 * (r >> 2) + 4 * q + rw;
            int grow = m0 + rloc;
            float v = acc[tn][r];
            if (grow < M) yout[grow * 128 + col] = v;
            s += v; sq += v * v;
        }
        s += __shfl_xor(s, 32);
        sq += __shfl_xor(sq, 32);
        if (lane < 32) {
            atomicAdd(&stats[col], s);
            atomicAdd(&stats[128 + col], sq);
        }
    }
}

// ---------------------------------------------------------------------------
// BN (batch stats) + ReLU -> bf16 (optionally + residual)
// ---------------------------------------------------------------------------
__global__ void bn_relu_kernel(const float* __restrict__ y, const float* __restrict__ stats,
                               const float* __restrict__ g, const float* __restrict__ b,
                               unsigned short* __restrict__ out, int total4, float invM) {
    int idx = blockIdx.x * 256 + threadIdx.x;
    if (idx >= total4) return;
    int e0 = idx * 4;
    int c0 = e0 & 127;
    float4 yv = *(const float4*)(y + e0);
    float h[4];
    const float* yp = (const float*)&yv;
#pragma unroll
    for (int j = 0; j < 4; ++j) {
        int c = c0 + j;
        float mean = stats[c] * invM;
        float var = stats[128 + c] * invM - mean * mean;
        float sc = g[c] * rsqrtf(var + LN_EPS);
        float sh = b[c] - mean * sc;
        float vv = yp[j] * sc + sh;
        h[j] = vv > 0.f ? vv : 0.f;
    }
    uint2 pk;
    pk.x = f2bf_rne(h[0]) | (f2bf_rne(h[1]) << 16);
    pk.y = f2bf_rne(h[2]) | (f2bf_rne(h[3]) << 16);
    *(uint2*)(out + e0) = pk;
}

__global__ void bn_relu_res_kernel(const float* __restrict__ y, const float* __restrict__ stats,
                                   const float* __restrict__ g, const float* __restrict__ b,
                                   const unsigned short* __restrict__ idn,
                                   unsigned short* __restrict__ out, int total4, float invM) {
    int idx = blockIdx.x * 256 + threadIdx.x;
    if (idx >= total4) return;
    int e0 = idx * 4;
    int c0 = e0 & 127;
    float4 yv = *(const float4*)(y + e0);
    uint2 iv = *(const uint2*)(idn + e0);
    float id[4];
    id[0] = __uint_as_float(iv.x << 16);
    id[1] = __uint_as_float(iv.x & 0xffff0000u);
    id[2] = __uint_as_float(iv.y << 16);
    id[3] = __uint_as_float(iv.y & 0xffff0000u);
    float h[4];
    const float* yp = (const float*)&yv;
#pragma unroll
    for (int j = 0; j < 4; ++j) {
        int c = c0 + j;
        float mean = stats[c] * invM;
        float var = stats[128 + c] * invM - mean * mean;
        float sc = g[c] * rsqrtf(var + LN_EPS);
        float sh = b[c] - mean * sc;
        float vv = yp[j] * sc + sh + id[j];
        h[j] = vv > 0.f ? vv : 0.f;
    }
    uint2 pk;
    pk.x = f2bf_rne(h[0]) | (f2bf_rne(h[1]) << 16);
    pk.y = f2bf_rne(h[2]) | (f2bf_rne(h[3]) << 16);
    *(uint2*)(out + e0) = pk;
}

// ---------------------------------------------------------------------------
// Head over voxels: Dv = relu(A @ w1 + b1) @ w2
// ---------------------------------------------------------------------------
__global__ __launch_bounds__(256) void head_vox_kernel(
    const unsigned short* __restrict__ A,    // (M+1) x 128 bf16
    const unsigned short* __restrict__ Wp1,  // 8 x 64 x 8 bf16 packed
    const float* __restrict__ b1, const float* __restrict__ w2,
    const float* __restrict__ b2, float* __restrict__ Dv, int M)
{
    __shared__ uint4 W1s[1024];          // 16 KB
    __shared__ unsigned short Hs[8192];  // 128 x 64 bf16, chunk-swizzled
    __shared__ float w2s[896];           // 64 x 14

    const int tid = threadIdx.x;
    const int lane = tid & 63;
    const int w = tid >> 6;
    const int m0 = blockIdx.x * 128;
    const int rw = w * 32;
    const int q = lane >> 5;
    const int l31 = lane & 31;
    int myrow = m0 + rw + l31;
    if (myrow > M) myrow = M;  // row M is zeros

#pragma unroll
    for (int rep = 0; rep < 4; ++rep) {
        __builtin_amdgcn_global_load_lds(
            (const AS1 unsigned int*)((const uint4*)Wp1 + rep * 256 + tid),
            (AS3 unsigned int*)(W1s + rep * 256 + w * 64), 16, 0, 0);
    }
    for (int i = tid; i < 896; i += 256) w2s[i] = w2[i];

    const uint4* xin4 = (const uint4*)A;
    uint4 af[8];
#pragma unroll
    for (int j = 0; j < 8; ++j) af[j] = xin4[myrow * 16 + 2 * j + q];

    f32x16 acc[2];
#pragma unroll
    for (int t = 0; t < 2; ++t)
#pragma unroll
        for (int r = 0; r < 16; ++r) acc[t][r] = 0.f;

    __syncthreads();

#pragma unroll
    for (int ks = 0; ks < 8; ++ks) {
        int kb = (ks << 1) | q;
        bf16x8 a = *(const bf16x8*)&af[ks];
#pragma unroll
        for (int tn = 0; tn < 2; ++tn) {
            bf16x8 b = ((const bf16x8*)W1s)[kb * 64 + tn * 32 + l31];
            acc[tn] = __builtin_amdgcn_mfma_f32_32x32x16_bf16(a, b, acc[tn], 0, 0, 0);
        }
    }

#pragma unroll
    for (int tn = 0; tn < 2; ++tn) {
        int col = tn * 32 + l31;
        float bias = b1[col];
        int ch = col >> 3, ce = col & 7;
#pragma unroll
        for (int r = 0; r < 16; ++r) {
            int rloc = (r & 3) + 8 * (r >> 2) + 4 * q + rw;
            float v = acc[tn][r] + bias;
            v = v > 0.f ? v : 0.f;
            Hs[rloc * 64 + (ch ^ (rloc & 7)) * 8 + ce] = (unsigned short)f2bf_rne(v);
        }
    }
    __syncthreads();

    int r2 = tid >> 1;
    int c0 = (tid & 1) * 7;
    float o[7];
#pragma unroll
    for (int j = 0; j < 7; ++j) o[j] = b2[c0 + j];
#pragma unroll
    for (int c = 0; c < 8; ++c) {
        bf16x8 hv = ((const bf16x8*)Hs)[r2 * 8 + (c ^ (r2 & 7))];
#pragma unroll
        for (int e = 0; e < 8; ++e) {
            float h = bf2f(((const unsigned short*)&hv)[e]);
            int k = c * 8 + e;
#pragma unroll
            for (int j = 0; j < 7; ++j) o[j] = fmaf(h, w2s[k * 14 + c0 + j], o[j]);
        }
    }
    int grow = m0 + r2;
    if (grow < M) {
#pragma unroll
        for (int j = 0; j < 7; ++j) Dv[grow * 14 + c0 + j] = o[j];
    }
}

// out[p] = gp[p,:14] + Dv[inv_idx[p]]
__global__ void head_scatter_kernel(const float* __restrict__ gp, const float* __restrict__ Dv,
                                    const int* __restrict__ inv_idx, float* __restrict__ out, int N) {
    int p = blockIdx.x * 256 + threadIdx.x;
    if (p >= N) return;
    int vx = inv_idx[p];
#pragma unroll
    for (int c = 0; c < 14; ++c) out[p * 14 + c] = gp[p * 14 + c] + Dv[vx * 14 + c];
}

// ---------------------------------------------------------------------------
extern "C" void kernel_launch(void* const* d_in, const int* in_sizes, int n_in,
                              void* d_out, int out_size, void* d_ws, size_t ws_size,
                              hipStream_t stream) {
    const float* gp       = (const float*)d_in[0];
    const float* w_enc    = (const float*)d_in[1];
    const float* b_enc    = (const float*)d_in[2];
    const float* ln_g     = (const float*)d_in[3];
    const float* ln_b     = (const float*)d_in[4];
    const float* conv_w   = (const float*)d_in[5];
    const float* bn_g     = (const float*)d_in[6];
    const float* bn_b     = (const float*)d_in[7];
    const float* w1       = (const float*)d_in[8];
    const float* b1       = (const float*)d_in[9];
    const float* w2       = (const float*)d_in[10];
    const float* b2       = (const float*)d_in[11];
    const float* nbr_mask = (const float*)d_in[12];
    const int*   inv_idx  = (const int*)d_in[13];
    const int*   nbr_idx  = (const int*)d_in[14];

    const int N = in_sizes[0] / 14;
    const int M = in_sizes[12] / 27;
    const int ntiles256 = (M + 255) / 256;   // conv tiles
    const int ntiles128 = (M + 127) / 128;   // head tiles
    const int nb = (M + 1023) / 1024;        // scan blocks

    char* ws = (char*)d_ws;
    size_t off = 0;
    unsigned short* Wp  = (unsigned short*)(ws + off); off += (size_t)4 * 27 * 16384 * 2;
    unsigned short* Wp1 = (unsigned short*)(ws + off); off += 8192 * 2;
    unsigned short* A   = (unsigned short*)(ws + off); off += (size_t)(M + 1) * 128 * 2;
    unsigned short* H   = (unsigned short*)(ws + off); off += (size_t)(M + 1) * 128 * 2;
    float* Yraw  = (float*)(ws + off); off += (size_t)M * 128 * 4;  // conv out; reused as Dv
    int* T       = (int*)(ws + off); off += (size_t)27 * M * 4;
    int* starts  = (int*)(ws + off); off += (size_t)M * 4;
    int* plist   = (int*)(ws + off); off += (size_t)N * 4;
    int* partials= (int*)(ws + off); off += 1024 * 4;
    // --- contiguous zeroed region ---
    size_t zoff = off;
    int* cnt     = (int*)(ws + off); off += (size_t)M * 4;
    int* tmp     = (int*)(ws + off); off += (size_t)M * 4;
    float* stats = (float*)(ws + off); off += 4 * 256 * 4;
    unsigned* act= (unsigned*)(ws + off); off += (size_t)ntiles256 * 4;
    size_t zbytes = off - zoff;
    float* Dv = Yraw;

    hipMemsetAsync(cnt, 0, zbytes, stream);
    hipMemsetAsync(A + (size_t)M * 128, 0, 256, stream);  // dummy zero rows
    hipMemsetAsync(H + (size_t)M * 128, 0, 256, stream);

    const int E = 4 * 27 * 128 * 128;
    pack_w_kernel<<<(E + 255) / 256, 256, 0, stream>>>(conv_w, Wp, E);
    pack_w1_kernel<<<32, 256, 0, stream>>>(w1, Wp1);
    prep_nbr_kernel<<<(M + 255) / 256, 256, 0, stream>>>(nbr_idx, nbr_mask, T, act, M);

    // CSR build + voxel encode (replaces atomic scatter encoder)
    count_kernel<<<(N + 255) / 256, 256, 0, stream>>>(inv_idx, cnt, N);
    scan1_kernel<<<nb, 256, 0, stream>>>(cnt, starts, partials, M);
    scan2_kernel<<<1, 256, 0, stream>>>(partials, nb);
    fill_kernel<<<(N + 255) / 256, 256, 0, stream>>>(inv_idx, starts, partials, tmp, plist, N);
    vox_encode_kernel<<<(M + 3) / 4, 256, 0, stream>>>(
        gp, w_enc, b_enc, ln_g, ln_b, starts, partials, cnt, plist, A, M);

    const int total4 = M * 32;
    const float invM = 1.f / (float)M;
    for (int blk = 0; blk < 2; ++blk) {
        int c0 = 2 * blk, c1 = 2 * blk + 1;
        subm_conv_kernel<<<ntiles256, 512, 0, stream>>>(
            A, Wp + (size_t)c0 * 27 * 16384, T, act, Yraw, stats + c0 * 256, M);
        bn_relu_kernel<<<(total4 + 255) / 256, 256, 0, stream>>>(
            Yraw, stats + c0 * 256, bn_g + c0 * 128, bn_b + c0 * 128, H, total4, invM);
        subm_conv_kernel<<<ntiles256, 512, 0, stream>>>(
            H, Wp + (size_t)c1 * 27 * 16384, T, act, Yraw, stats + c1 * 256, M);
        bn_relu_res_kernel<<<(total4 + 255) / 256, 256, 0, stream>>>(
            Yraw, stats + c1 * 256, bn_g + c1 * 128, bn_b + c1 * 128, A, A, total4, invM);
    }
    head_vox_kernel<<<ntiles128, 256, 0, stream>>>(A, Wp1, b1, w2, b2, Dv, M);
    head_scatter_kernel<<<(N + 255) / 256, 256, 0, stream>>>(gp, Dv, inv_idx, (float*)d_out, N);
}

// Round 5
// 1551.166 us; speedup vs baseline: 1.1219x; 1.1219x over previous
//
#include <hip/hip_runtime.h>

typedef __bf16 bf16x8 __attribute__((ext_vector_type(8)));
typedef float f32x16 __attribute__((ext_vector_type(16)));

#define LN_EPS 1e-5f
#define AS1 __attribute__((address_space(1)))
#define AS3 __attribute__((address_space(3)))

__device__ __forceinline__ unsigned f2bf_rne(float f) {
    unsigned x = __float_as_uint(f);
    return (x + 0x7fffu + ((x >> 16) & 1u)) >> 16;  // round-to-nearest-even, finite inputs
}

__device__ __forceinline__ float bf2f(unsigned short u) {
    return __uint_as_float((unsigned)u << 16);
}

// ---------------------------------------------------------------------------
// Pack conv_w fp32 (4,27,128,128) -> bf16, K-packed by 8: Wp[oc][k>>3][n][k&7]
// ---------------------------------------------------------------------------
__global__ void pack_w_kernel(const float* __restrict__ cw, unsigned short* __restrict__ Wp, int E) {
    int idx = blockIdx.x * 256 + threadIdx.x;
    if (idx >= E) return;
    float v = cw[idx];
    int n  = idx & 127;
    int c  = (idx >> 7) & 127;
    int oc = idx >> 14;
    Wp[oc * 16384 + (c >> 3) * 1024 + n * 8 + (c & 7)] = (unsigned short)f2bf_rne(v);
}

// Pack w1 fp32 (128,64) -> bf16 K-packed: Wp1[k>>3][n][k&7]
__global__ void pack_w1_kernel(const float* __restrict__ w1, unsigned short* __restrict__ Wp1) {
    int idx = blockIdx.x * 256 + threadIdx.x;
    if (idx >= 8192) return;
    int k = idx >> 6, n = idx & 63;
    Wp1[(k >> 3) * 512 + n * 8 + (k & 7)] = (unsigned short)f2bf_rne(w1[k * 64 + n]);
}

// ---------------------------------------------------------------------------
// Prep: gather table T[o][m] = found ? nbr_idx : M (dummy zero row),
// per-128-tile activity bitmask act[tile].
// ---------------------------------------------------------------------------
__global__ void prep_nbr_kernel(const int* __restrict__ nbr_idx, const float* __restrict__ nbr_mask,
                                int* __restrict__ T, unsigned* __restrict__ act, int M) {
    int m = blockIdx.x * 256 + threadIdx.x;
    if (m >= M) return;
    unsigned bits = 0;
#pragma unroll
    for (int o = 0; o < 27; ++o) {
        bool f = nbr_mask[m * 27 + o] != 0.f;
        int g = f ? nbr_idx[m * 27 + o] : M;
        T[o * M + m] = g;
        bits |= (f ? 1u : 0u) << o;
    }
    atomicOr(&act[m >> 7], bits);
}

// ---------------------------------------------------------------------------
// CSR build: count -> scan (2-level) -> fill
// ---------------------------------------------------------------------------
__global__ void count_kernel(const int* __restrict__ inv, int* __restrict__ cnt, int N) {
    int p = blockIdx.x * 256 + threadIdx.x;
    if (p < N) atomicAdd(&cnt[inv[p]], 1);
}

__global__ void scan1_kernel(const int* __restrict__ cnt, int* __restrict__ starts,
                             int* __restrict__ partials, int M) {
    __shared__ int sdata[256];
    int t = threadIdx.x;
    int base = blockIdx.x * 1024;
    int v[4], tot = 0;
#pragma unroll
    for (int j = 0; j < 4; ++j) {
        int idx = base + t * 4 + j;
        v[j] = idx < M ? cnt[idx] : 0;
        tot += v[j];
    }
    sdata[t] = tot;
    __syncthreads();
    for (int off = 1; off < 256; off <<= 1) {
        int x = (t >= off) ? sdata[t - off] : 0;
        __syncthreads();
        sdata[t] += x;
        __syncthreads();
    }
    int run = sdata[t] - tot;
#pragma unroll
    for (int j = 0; j < 4; ++j) {
        int idx = base + t * 4 + j;
        if (idx < M) starts[idx] = run;
        run += v[j];
    }
    if (t == 255) partials[blockIdx.x] = run;
}

__global__ void scan2_kernel(int* __restrict__ partials, int nb) {
    __shared__ int sdata[256];
    int t = threadIdx.x;
    int v[4], tot = 0;
#pragma unroll
    for (int j = 0; j < 4; ++j) {
        int idx = t * 4 + j;
        v[j] = idx < nb ? partials[idx] : 0;
        tot += v[j];
    }
    sdata[t] = tot;
    __syncthreads();
    for (int off = 1; off < 256; off <<= 1) {
        int x = (t >= off) ? sdata[t - off] : 0;
        __syncthreads();
        sdata[t] += x;
        __syncthreads();
    }
    int run = sdata[t] - tot;
#pragma unroll
    for (int j = 0; j < 4; ++j) {
        int idx = t * 4 + j;
        if (idx < nb) partials[idx] = run;
        run += v[j];
    }
}

__global__ void fill_kernel(const int* __restrict__ inv, const int* __restrict__ starts,
                            const int* __restrict__ partials, int* __restrict__ tmp,
                            int* __restrict__ plist, int N) {
    int p = blockIdx.x * 256 + threadIdx.x;
    if (p >= N) return;
    int v = inv[p];
    int slot = atomicAdd(&tmp[v], 1);
    plist[starts[v] + partials[v >> 10] + slot] = p;
}

// ---------------------------------------------------------------------------
// Voxel encoder: A[v] = mean over points p in voxel of relu(LN(gp[p] @ w_enc + b)).
// One wave per voxel; lane owns channels {2*lane, 2*lane+1}.
// ---------------------------------------------------------------------------
__global__ __launch_bounds__(256) void vox_encode_kernel(
    const float* __restrict__ gp, const float* __restrict__ w_enc,
    const float* __restrict__ b_enc, const float* __restrict__ ln_g,
    const float* __restrict__ ln_b, const int* __restrict__ starts,
    const int* __restrict__ partials, const int* __restrict__ cnt,
    const int* __restrict__ plist, unsigned short* __restrict__ A, int M)
{
    int v = blockIdx.x * 4 + (threadIdx.x >> 6);
    int lane = threadIdx.x & 63;
    if (v >= M) return;
    int st = starts[v] + partials[v >> 10];
    int n = cnt[v];
    const float2* w2p = (const float2*)w_enc;
    float2 be = ((const float2*)b_enc)[lane];
    float2 lg = ((const float2*)ln_g)[lane];
    float2 lb = ((const float2*)ln_b)[lane];
    float a0 = 0.f, a1 = 0.f;
    for (int i = 0; i < n; ++i) {
        int p = plist[st + i];
        float f0 = be.x, f1 = be.y;
#pragma unroll
        for (int k = 0; k < 14; ++k) {
            float gv = gp[p * 14 + k];
            float2 wv = w2p[k * 64 + lane];
            f0 = fmaf(gv, wv.x, f0);
            f1 = fmaf(gv, wv.y, f1);
        }
        float s = f0 + f1;
#pragma unroll
        for (int off = 32; off; off >>= 1) s += __shfl_xor(s, off);
        float mean = s * 0.0078125f;
        float d0 = f0 - mean, d1 = f1 - mean;
        float var = d0 * d0 + d1 * d1;
#pragma unroll
        for (int off = 32; off; off >>= 1) var += __shfl_xor(var, off);
        float rs = rsqrtf(var * 0.0078125f + LN_EPS);
        float h0 = d0 * rs * lg.x + lb.x;
        float h1 = d1 * rs * lg.y + lb.y;
        a0 += h0 > 0.f ? h0 : 0.f;
        a1 += h1 > 0.f ? h1 : 0.f;
    }
    float r = 1.f / (float)n;
    ((unsigned*)A)[v * 64 + lane] = f2bf_rne(a0 * r) | (f2bf_rne(a1 * r) << 16);
}

// ---------------------------------------------------------------------------
// Submanifold conv, fully prefetched: 128 voxels x 128 ch per block, 4 waves.
// W double-buffered in LDS (2x32KB), A-gather double-buffered in REGISTERS.
// Per offset: one barrier; every load it drains was issued >= 1 MFMA-phase
// earlier (stage(o+1) and gather(o+1) both issued before MFMA(o)).
// ---------------------------------------------------------------------------
__global__ __launch_bounds__(256, 2) void subm_conv_kernel(
    const unsigned short* __restrict__ xin,   // (M+1) x 128 bf16, row M zeros
    const unsigned short* __restrict__ Wp,    // 27 x 16 x 128 x 8 bf16 packed
    const int* __restrict__ T, const unsigned* __restrict__ act,
    float* __restrict__ yout, float* __restrict__ stats, int M)
{
    __shared__ uint4 Ws[2][2048];  // 64 KB

    const int tid = threadIdx.x;
    const int lane = tid & 63;
    const int w = tid >> 6;
    const int m0 = blockIdx.x * 128;
    const int rw = w * 32;
    const int q = lane >> 5;
    const int l31 = lane & 31;
    int myrow = m0 + rw + l31;
    if (myrow >= M) myrow = M - 1;  // gather-table guard (stores/stats guarded below)

    f32x16 acc[4];
#pragma unroll
    for (int t = 0; t < 4; ++t)
#pragma unroll
        for (int r = 0; r < 16; ++r) acc[t][r] = 0.f;

    const uint4* xin4 = (const uint4*)xin;
    unsigned amask = act[blockIdx.x];
    int o_cur = __ffs(amask) - 1;  // center offset always active => amask != 0
    amask &= amask - 1;
    int buf = 0;
    uint4 afA[8], afB[8];

    {   // prologue: stage W(o0) -> Ws[0], gather A(o0) -> afA
        const uint4* WpO4 = (const uint4*)Wp + o_cur * 2048;
#pragma unroll
        for (int rep = 0; rep < 8; ++rep)
            __builtin_amdgcn_global_load_lds(
                (const AS1 unsigned int*)(WpO4 + rep * 256 + tid),
                (AS3 unsigned int*)(&Ws[0][rep * 256 + w * 64]), 16, 0, 0);
        int g = T[o_cur * M + myrow];
#pragma unroll
        for (int j = 0; j < 8; ++j) afA[j] = xin4[g * 16 + 2 * j + q];
    }

    // one pipeline step: barrier; prefetch (W+A) for o_next; MFMA on current
    auto conv_step = [&](uint4 (&afC)[8], uint4 (&afN)[8]) {
        int o_next = -1;
        if (amask) { o_next = __ffs(amask) - 1; amask &= amask - 1; }
        __syncthreads();  // drains stage(cur)+gather(cur), both >=1 phase old
        if (o_next >= 0) {
            const uint4* WpO4 = (const uint4*)Wp + o_next * 2048;
#pragma unroll
            for (int rep = 0; rep < 8; ++rep)
                __builtin_amdgcn_global_load_lds(
                    (const AS1 unsigned int*)(WpO4 + rep * 256 + tid),
                    (AS3 unsigned int*)(&Ws[buf ^ 1][rep * 256 + w * 64]), 16, 0, 0);
            int g = T[o_next * M + myrow];
#pragma unroll
            for (int j = 0; j < 8; ++j) afN[j] = xin4[g * 16 + 2 * j + q];
        }
        const bf16x8* wsb = (const bf16x8*)&Ws[buf][0];
#pragma unroll
        for (int ks = 0; ks < 8; ++ks) {
            int kb = (ks << 1) | q;
            bf16x8 a = *(const bf16x8*)&afC[ks];
#pragma unroll
            for (int tn = 0; tn < 4; ++tn) {
                bf16x8 b = wsb[kb * 128 + tn * 32 + l31];
                acc[tn] = __builtin_amdgcn_mfma_f32_32x32x16_bf16(a, b, acc[tn], 0, 0, 0);
            }
        }
        buf ^= 1;
        o_cur = o_next;
    };

    while (o_cur >= 0) {
        conv_step(afA, afB);
        if (o_cur < 0) break;
        conv_step(afB, afA);
    }

    // ---- epilogue: store y + BN stats (guard rows excluded from stats) ----
#pragma unroll
    for (int tn = 0; tn < 4; ++tn) {
        int col = tn * 32 + l31;
        float s = 0.f, sq = 0.f;
#pragma unroll
        for (int r = 0; r < 16; ++r) {
            int rloc = (r & 3) + 8 * (r >> 2) + 4 * q + rw;
            int grow = m0 + rloc;
            float v = acc[tn][r];
            if (grow < M) {
                yout[grow * 128 + col] = v;
                s += v; sq += v * v;
            }
        }
        s += __shfl_xor(s, 32);
        sq += __shfl_xor(sq, 32);
        if (lane < 32) {
            atomicAdd(&stats[col], s);
            atomicAdd(&stats[128 + col], sq);
        }
    }
}

// ---------------------------------------------------------------------------
// BN (batch stats) + ReLU -> bf16 (optionally + residual)
// ---------------------------------------------------------------------------
__global__ void bn_relu_kernel(const float* __restrict__ y, const float* __restrict__ stats,
                               const float* __restrict__ g, const float* __restrict__ b,
                               unsigned short* __restrict__ out, int total4, float invM) {
    int idx = blockIdx.x * 256 + threadIdx.x;
    if (idx >= total4) return;
    int e0 = idx * 4;
    int c0 = e0 & 127;
    float4 yv = *(const float4*)(y + e0);
    float h[4];
    const float* yp = (const float*)&yv;
#pragma unroll
    for (int j = 0; j < 4; ++j) {
        int c = c0 + j;
        float mean = stats[c] * invM;
        float var = stats[128 + c] * invM - mean * mean;
        float sc = g[c] * rsqrtf(var + LN_EPS);
        float sh = b[c] - mean * sc;
        float vv = yp[j] * sc + sh;
        h[j] = vv > 0.f ? vv : 0.f;
    }
    uint2 pk;
    pk.x = f2bf_rne(h[0]) | (f2bf_rne(h[1]) << 16);
    pk.y = f2bf_rne(h[2]) | (f2bf_rne(h[3]) << 16);
    *(uint2*)(out + e0) = pk;
}

__global__ void bn_relu_res_kernel(const float* __restrict__ y, const float* __restrict__ stats,
                                   const float* __restrict__ g, const float* __restrict__ b,
                                   const unsigned short* __restrict__ idn,
                                   unsigned short* __restrict__ out, int total4, float invM) {
    int idx = blockIdx.x * 256 + threadIdx.x;
    if (idx >= total4) return;
    int e0 = idx * 4;
    int c0 = e0 & 127;
    float4 yv = *(const float4*)(y + e0);
    uint2 iv = *(const uint2*)(idn + e0);
    float id[4];
    id[0] = __uint_as_float(iv.x << 16);
    id[1] = __uint_as_float(iv.x & 0xffff0000u);
    id[2] = __uint_as_float(iv.y << 16);
    id[3] = __uint_as_float(iv.y & 0xffff0000u);
    float h[4];
    const float* yp = (const float*)&yv;
#pragma unroll
    for (int j = 0; j < 4; ++j) {
        int c = c0 + j;
        float mean = stats[c] * invM;
        float var = stats[128 + c] * invM - mean * mean;
        float sc = g[c] * rsqrtf(var + LN_EPS);
        float sh = b[c] - mean * sc;
        float vv = yp[j] * sc + sh + id[j];
        h[j] = vv > 0.f ? vv : 0.f;
    }
    uint2 pk;
    pk.x = f2bf_rne(h[0]) | (f2bf_rne(h[1]) << 16);
    pk.y = f2bf_rne(h[2]) | (f2bf_rne(h[3]) << 16);
    *(uint2*)(out + e0) = pk;
}

// ---------------------------------------------------------------------------
// Head over voxels: Dv = relu(A @ w1 + b1) @ w2
// ---------------------------------------------------------------------------
__global__ __launch_bounds__(256) void head_vox_kernel(
    const unsigned short* __restrict__ A,    // (M+1) x 128 bf16
    const unsigned short* __restrict__ Wp1,  // 8 x 64 x 8 bf16 packed
    const float* __restrict__ b1, const float* __restrict__ w2,
    const float* __restrict__ b2, float* __restrict__ Dv, int M)
{
    __shared__ uint4 W1s[1024];          // 16 KB
    __shared__ unsigned short Hs[8192];  // 128 x 64 bf16, chunk-swizzled
    __shared__ float w2s[896];           // 64 x 14

    const int tid = threadIdx.x;
    const int lane = tid & 63;
    const int w = tid >> 6;
    const int m0 = blockIdx.x * 128;
    const int rw = w * 32;
    const int q = lane >> 5;
    const int l31 = lane & 31;
    int myrow = m0 + rw + l31;
    if (myrow > M) myrow = M;  // row M is zeros

#pragma unroll
    for (int rep = 0; rep < 4; ++rep) {
        __builtin_amdgcn_global_load_lds(
            (const AS1 unsigned int*)((const uint4*)Wp1 + rep * 256 + tid),
            (AS3 unsigned int*)(W1s + rep * 256 + w * 64), 16, 0, 0);
    }
    for (int i = tid; i < 896; i += 256) w2s[i] = w2[i];

    const uint4* xin4 = (const uint4*)A;
    uint4 af[8];
#pragma unroll
    for (int j = 0; j < 8; ++j) af[j] = xin4[myrow * 16 + 2 * j + q];

    f32x16 acc[2];
#pragma unroll
    for (int t = 0; t < 2; ++t)
#pragma unroll
        for (int r = 0; r < 16; ++r) acc[t][r] = 0.f;

    __syncthreads();

#pragma unroll
    for (int ks = 0; ks < 8; ++ks) {
        int kb = (ks << 1) | q;
        bf16x8 a = *(const bf16x8*)&af[ks];
#pragma unroll
        for (int tn = 0; tn < 2; ++tn) {
            bf16x8 b = ((const bf16x8*)W1s)[kb * 64 + tn * 32 + l31];
            acc[tn] = __builtin_amdgcn_mfma_f32_32x32x16_bf16(a, b, acc[tn], 0, 0, 0);
        }
    }

#pragma unroll
    for (int tn = 0; tn < 2; ++tn) {
        int col = tn * 32 + l31;
        float bias = b1[col];
        int ch = col >> 3, ce = col & 7;
#pragma unroll
        for (int r = 0; r < 16; ++r) {
            int rloc = (r & 3) + 8 * (r >> 2) + 4 * q + rw;
            float v = acc[tn][r] + bias;
            v = v > 0.f ? v : 0.f;
            Hs[rloc * 64 + (ch ^ (rloc & 7)) * 8 + ce] = (unsigned short)f2bf_rne(v);
        }
    }
    __syncthreads();

    int r2 = tid >> 1;
    int c0 = (tid & 1) * 7;
    float o[7];
#pragma unroll
    for (int j = 0; j < 7; ++j) o[j] = b2[c0 + j];
#pragma unroll
    for (int c = 0; c < 8; ++c) {
        bf16x8 hv = ((const bf16x8*)Hs)[r2 * 8 + (c ^ (r2 & 7))];
#pragma unroll
        for (int e = 0; e < 8; ++e) {
            float h = bf2f(((const unsigned short*)&hv)[e]);
            int k = c * 8 + e;
#pragma unroll
            for (int j = 0; j < 7; ++j) o[j] = fmaf(h, w2s[k * 14 + c0 + j], o[j]);
        }
    }
    int grow = m0 + r2;
    if (grow < M) {
#pragma unroll
        for (int j = 0; j < 7; ++j) Dv[grow * 14 + c0 + j] = o[j];
    }
}

// out[p] = gp[p,:14] + Dv[inv_idx[p]]
__global__ void head_scatter_kernel(const float* __restrict__ gp, const float* __restrict__ Dv,
                                    const int* __restrict__ inv_idx, float* __restrict__ out, int N) {
    int p = blockIdx.x * 256 + threadIdx.x;
    if (p >= N) return;
    int vx = inv_idx[p];
#pragma unroll
    for (int c = 0; c < 14; ++c) out[p * 14 + c] = gp[p * 14 + c] + Dv[vx * 14 + c];
}

// ---------------------------------------------------------------------------
extern "C" void kernel_launch(void* const* d_in, const int* in_sizes, int n_in,
                              void* d_out, int out_size, void* d_ws, size_t ws_size,
                              hipStream_t stream) {
    const float* gp       = (const float*)d_in[0];
    const float* w_enc    = (const float*)d_in[1];
    const float* b_enc    = (const float*)d_in[2];
    const float* ln_g     = (const float*)d_in[3];
    const float* ln_b     = (const float*)d_in[4];
    const float* conv_w   = (const float*)d_in[5];
    const float* bn_g     = (const float*)d_in[6];
    const float* bn_b     = (const float*)d_in[7];
    const float* w1       = (const float*)d_in[8];
    const float* b1       = (const float*)d_in[9];
    const float* w2       = (const float*)d_in[10];
    const float* b2       = (const float*)d_in[11];
    const float* nbr_mask = (const float*)d_in[12];
    const int*   inv_idx  = (const int*)d_in[13];
    const int*   nbr_idx  = (const int*)d_in[14];

    const int N = in_sizes[0] / 14;
    const int M = in_sizes[12] / 27;
    const int ntiles128 = (M + 127) / 128;   // conv + head tiles
    const int nb = (M + 1023) / 1024;        // scan blocks

    char* ws = (char*)d_ws;
    size_t off = 0;
    unsigned short* Wp  = (unsigned short*)(ws + off); off += (size_t)4 * 27 * 16384 * 2;
    unsigned short* Wp1 = (unsigned short*)(ws + off); off += 8192 * 2;
    unsigned short* A   = (unsigned short*)(ws + off); off += (size_t)(M + 1) * 128 * 2;
    unsigned short* H   = (unsigned short*)(ws + off); off += (size_t)(M + 1) * 128 * 2;
    float* Yraw  = (float*)(ws + off); off += (size_t)M * 128 * 4;  // conv out; reused as Dv
    int* T       = (int*)(ws + off); off += (size_t)27 * M * 4;
    int* starts  = (int*)(ws + off); off += (size_t)M * 4;
    int* plist   = (int*)(ws + off); off += (size_t)N * 4;
    int* partials= (int*)(ws + off); off += 1024 * 4;
    // --- contiguous zeroed region ---
    size_t zoff = off;
    int* cnt     = (int*)(ws + off); off += (size_t)M * 4;
    int* tmp     = (int*)(ws + off); off += (size_t)M * 4;
    float* stats = (float*)(ws + off); off += 4 * 256 * 4;
    unsigned* act= (unsigned*)(ws + off); off += (size_t)ntiles128 * 4;
    size_t zbytes = off - zoff;
    float* Dv = Yraw;

    hipMemsetAsync(cnt, 0, zbytes, stream);
    hipMemsetAsync(A + (size_t)M * 128, 0, 256, stream);  // dummy zero rows
    hipMemsetAsync(H + (size_t)M * 128, 0, 256, stream);

    const int E = 4 * 27 * 128 * 128;
    pack_w_kernel<<<(E + 255) / 256, 256, 0, stream>>>(conv_w, Wp, E);
    pack_w1_kernel<<<32, 256, 0, stream>>>(w1, Wp1);
    prep_nbr_kernel<<<(M + 255) / 256, 256, 0, stream>>>(nbr_idx, nbr_mask, T, act, M);

    // CSR build + voxel encode
    count_kernel<<<(N + 255) / 256, 256, 0, stream>>>(inv_idx, cnt, N);
    scan1_kernel<<<nb, 256, 0, stream>>>(cnt, starts, partials, M);
    scan2_kernel<<<1, 256, 0, stream>>>(partials, nb);
    fill_kernel<<<(N + 255) / 256, 256, 0, stream>>>(inv_idx, starts, partials, tmp, plist, N);
    vox_encode_kernel<<<(M + 3) / 4, 256, 0, stream>>>(
        gp, w_enc, b_enc, ln_g, ln_b, starts, partials, cnt, plist, A, M);

    const int total4 = M * 32;
    const float invM = 1.f / (float)M;
    for (int blk = 0; blk < 2; ++blk) {
        int c0 = 2 * blk, c1 = 2 * blk + 1;
        subm_conv_kernel<<<ntiles128, 256, 0, stream>>>(
            A, Wp + (size_t)c0 * 27 * 16384, T, act, Yraw, stats + c0 * 256, M);
        bn_relu_kernel<<<(total4 + 255) / 256, 256, 0, stream>>>(
            Yraw, stats + c0 * 256, bn_g + c0 * 128, bn_b + c0 * 128, H, total4, invM);
        subm_conv_kernel<<<ntiles128, 256, 0, stream>>>(
            H, Wp + (size_t)c1 * 27 * 16384, T, act, Yraw, stats + c1 * 256, M);
        bn_relu_res_kernel<<<(total4 + 255) / 256, 256, 0, stream>>>(
            Yraw, stats + c1 * 256, bn_g + c1 * 128, bn_b + c1 * 128, A, A, total4, invM);
    }
    head_vox_kernel<<<ntiles128, 256, 0, stream>>>(A, Wp1, b1, w2, b2, Dv, M);
    head_scatter_kernel<<<(N + 255) / 256, 256, 0, stream>>>(gp, Dv, inv_idx, (float*)d_out, N);
}